// Round 3
// baseline (630.390 us; speedup 1.0000x reference)
//
#include <hip/hip_runtime.h>

// RichAttentionLayer: B=2048, S=200, D=192, H1=64, H2=32, IN=768.
// One block per batch b. Layer-1 decomposed:
//   x@W1 = k @ M_b + c_b,  M_b[d,h] = W1a[d,h] + W1d[d,h] + q[d]*W1c[d,h]
// v3: 32-row S-tiles (7), double-buffered kbuf, register prefetch 2 tiles
// ahead (staging latency off the critical path), LDS trimmed to ~37 KB ->
// 4 blocks/CU. GEMM1 h-split; GEMM2/softmax/o per-wave (8 rows each).

#define B_N 2048
#define S_N 200
#define D_N 192

typedef __bf16 bf16x8 __attribute__((ext_vector_type(8)));
typedef __bf16 bf16x4 __attribute__((ext_vector_type(4)));
typedef float  f32x4  __attribute__((ext_vector_type(4)));

struct __align__(16) Smem {
  unsigned char kbuf[2][32*400];      // bf16[32][200] (192 used), stride 400 B
  union {
    unsigned char h1buf[32*144];      // bf16[32][72] (64 used), stride 144 B
    struct { float opart[4][192]; float wm[4]; float wl[4]; } fin;
  };
  unsigned char w2t[32*136];          // bf16 w2t[k2][h] = W2[h][k2], stride 136 B
  union {
    struct { float qbuf[192]; float cpart[4][64]; } pb;   // phase A/B only
    float scores[224];                                    // main loop only
  };
  float cbuf[64];
  unsigned char maskbuf[224];
  float w3buf[32];
  float b2buf[32];
  float consts[4];                    // a1, a2, b3
};

__global__ __launch_bounds__(256, 4) void rich_attn_kernel(
    const float* __restrict__ query, const float* __restrict__ keys,
    const int*   __restrict__ keys_mask, const float* __restrict__ W1,
    const float* __restrict__ b1, const float* __restrict__ a1,
    const float* __restrict__ W2, const float* __restrict__ b2,
    const float* __restrict__ a2, const float* __restrict__ W3,
    const float* __restrict__ b3, float* __restrict__ out)
{
  __shared__ Smem sm;
  const int tid  = threadIdx.x;
  const int b    = blockIdx.x;
  const int wave = tid >> 6;
  const int lane = tid & 63;
  const int quad = (tid >> 4) & 3;
  const int n16  = tid & 15;

  const float* kb = keys + (size_t)b * (S_N * D_N);
  const int prow = tid / 8;           // staging: this thread's base row (0..31)
  const int pc4  = (tid & 7);         // and float4-column base (6 per thread)

  // ---- issue tile-0 key loads immediately (covered by phase A/B latency) ----
  float4 pre[6];
  #pragma unroll
  for (int i = 0; i < 6; ++i) {
    int f = tid + i*256, row = f / 48, c4 = f - row*48;
    pre[i] = ((const float4*)kb)[row*48 + c4];          // rows 0..31 all valid
  }

  // ---- phase A: q, mask, scalars, W2^T ----
  if (tid < 192) sm.pb.qbuf[tid] = query[b*D_N + tid];
  if (tid < 224) sm.maskbuf[tid] = (tid < 200) ? (unsigned char)(keys_mask[b*S_N + tid] != 0) : 0;
  if (tid < 32)  sm.w3buf[tid] = W3[tid];
  else if (tid < 64) sm.b2buf[tid-32] = b2[tid-32];
  if (tid == 64) { sm.consts[0] = a1[0]; sm.consts[1] = a2[0]; sm.consts[2] = b3[0]; }
  for (int i = tid; i < 64*32; i += 256) {
    int hh = i >> 5, kk = i & 31;
    *((__bf16*)&sm.w2t[kk*136 + hh*2]) = (__bf16)W2[i];
  }
  __syncthreads();

  // ---- phase B: c_b partials; fb1 (registers); fw2 ----
  {
    int hh = tid & 63, pp = tid >> 6;
    float acc = 0.f;
    int d0 = pp*48;
    #pragma unroll 4
    for (int d = d0; d < d0+48; ++d)
      acc += sm.pb.qbuf[d] * (W1[(192+d)*64 + hh] - W1[(576+d)*64 + hh]);
    sm.pb.cpart[pp][hh] = acc;
  }
  bf16x8 fb1[6];                      // B-frag: M_b[k=t*32+quad*8+j][n=h]
  {
    int h = (wave << 4) | n16;
    #pragma unroll
    for (int t = 0; t < 6; ++t)
      #pragma unroll
      for (int j = 0; j < 8; ++j) {
        int d = t*32 + quad*8 + j;
        float v = W1[d*64 + h] + W1[(576+d)*64 + h] + sm.pb.qbuf[d]*W1[(384+d)*64 + h];
        fb1[t][j] = (__bf16)v;
      }
  }
  bf16x8 fw2[2][2];
  #pragma unroll
  for (int nt2 = 0; nt2 < 2; ++nt2)
    #pragma unroll
    for (int t = 0; t < 2; ++t)
      fw2[nt2][t] = *(const bf16x8*)&sm.w2t[(nt2*16 + n16)*136 + (t*32 + quad*8)*2];
  const float w3v0 = sm.w3buf[n16], w3v1 = sm.w3buf[16 + n16];
  const float bbv0 = sm.b2buf[n16], bbv1 = sm.b2buf[16 + n16];
  const float a1v = sm.consts[0], a2v = sm.consts[1], b3v = sm.consts[2];
  __syncthreads();
  if (tid < 64)
    sm.cbuf[tid] = b1[tid] + sm.pb.cpart[0][tid] + sm.pb.cpart[1][tid]
                 + sm.pb.cpart[2][tid] + sm.pb.cpart[3][tid];

  // ---- prologue: write tile0 -> kbuf[0]; issue tile-1 loads ----
  #pragma unroll
  for (int i = 0; i < 6; ++i) {
    int f = tid + i*256, row = f / 48, c4 = f - row*48;
    float4 v = pre[i];
    bf16x4 bv; bv[0]=(__bf16)v.x; bv[1]=(__bf16)v.y; bv[2]=(__bf16)v.z; bv[3]=(__bf16)v.w;
    *(bf16x4*)&sm.kbuf[0][row*400 + c4*8] = bv;
  }
  #pragma unroll
  for (int i = 0; i < 6; ++i) {
    int f = tid + i*256, row = f / 48, c4 = f - row*48;
    int sg = 32 + row;
    pre[i] = ((const float4*)kb)[sg*48 + c4];           // rows 32..63 valid
  }
  __syncthreads();

  float m_run = -1e30f, l_run = 0.f;
  f32x4 o = {0.f, 0.f, 0.f, 0.f};     // lanes 0..47 own d = lane*4..+3 (per wave)

  for (int tile = 0; tile < 7; ++tile) {
    const int s0 = tile * 32;
    const unsigned char* cur = sm.kbuf[tile & 1];
    unsigned char* nxt = sm.kbuf[(tile + 1) & 1];

    // ---- stage tile+1 from regs; issue loads for tile+2 ----
    if (tile < 6) {
      #pragma unroll
      for (int i = 0; i < 6; ++i) {
        int f = tid + i*256, row = f / 48, c4 = f - row*48;
        float4 v = pre[i];
        bf16x4 bv; bv[0]=(__bf16)v.x; bv[1]=(__bf16)v.y; bv[2]=(__bf16)v.z; bv[3]=(__bf16)v.w;
        *(bf16x4*)&nxt[row*400 + c4*8] = bv;
      }
      if (tile < 5) {
        #pragma unroll
        for (int i = 0; i < 6; ++i) {
          int f = tid + i*256, row = f / 48, c4 = f - row*48;
          int sg = (tile + 2)*32 + row;
          float4 v = make_float4(0.f,0.f,0.f,0.f);
          if (sg < 200) v = ((const float4*)kb)[sg*48 + c4];
          pre[i] = v;
        }
      }
    }

    // ---- GEMM1: h1_pre[32 x 64]; wave owns h-cols [16w,16w+16) ----
    f32x4 acc1[2];
    acc1[0] = (f32x4){0.f,0.f,0.f,0.f};
    acc1[1] = (f32x4){0.f,0.f,0.f,0.f};
    #pragma unroll
    for (int t = 0; t < 6; ++t)
      #pragma unroll
      for (int mt = 0; mt < 2; ++mt) {
        bf16x8 fa = *(const bf16x8*)&cur[(mt*16 + n16)*400 + (t*32 + quad*8)*2];
        acc1[mt] = __builtin_amdgcn_mfma_f32_16x16x32_bf16(fa, fb1[t], acc1[mt], 0, 0, 0);
      }
    {
      int h = (wave << 4) | n16;
      float cb = sm.cbuf[h];
      #pragma unroll
      for (int mt = 0; mt < 2; ++mt)
        #pragma unroll
        for (int r = 0; r < 4; ++r) {
          int m = mt*16 + quad*4 + r;
          float v = acc1[mt][r] + cb;
          v = (v >= 0.f) ? v : a1v * v;
          *((__bf16*)&sm.h1buf[m*144 + h*2]) = (__bf16)v;
        }
    }
    __syncthreads();   // h1 ready; nxt staged

    // ---- per-wave: rows wave*8 .. wave*8+7 of this tile ----
    bf16x8 fa2[2];
    #pragma unroll
    for (int t = 0; t < 2; ++t)
      fa2[t] = *(const bf16x8*)&sm.h1buf[(wave*8 + (n16 & 7))*144 + (t*32 + quad*8)*2];
    f32x4 acc2[2];
    acc2[0] = (f32x4){0.f,0.f,0.f,0.f};
    acc2[1] = (f32x4){0.f,0.f,0.f,0.f};
    #pragma unroll
    for (int nt2 = 0; nt2 < 2; ++nt2)
      #pragma unroll
      for (int t = 0; t < 2; ++t)
        acc2[nt2] = __builtin_amdgcn_mfma_f32_16x16x32_bf16(fa2[t], fw2[nt2][t], acc2[nt2], 0, 0, 0);

    float sc[4];
    #pragma unroll
    for (int r = 0; r < 4; ++r) {
      float v0 = acc2[0][r] + bbv0; v0 = (v0 >= 0.f) ? v0 : a2v * v0;
      float v1 = acc2[1][r] + bbv1; v1 = (v1 >= 0.f) ? v1 : a2v * v1;
      sc[r] = v0 * w3v0 + v1 * w3v1;
    }
    #pragma unroll
    for (int off = 1; off < 16; off <<= 1)
      #pragma unroll
      for (int r = 0; r < 4; ++r) sc[r] += __shfl_xor(sc[r], off);

    float p[4];
    float mloc = -1e30f;
    #pragma unroll
    for (int r = 0; r < 4; ++r) {
      int m = quad*4 + r;                       // row within wave's 16; valid m<8
      int sg = s0 + wave*8 + m;
      sc[r] += b3v;
      bool valid = (m < 8) && (sg < 200) && (sm.maskbuf[sg < 224 ? sg : 0] != 0);
      sc[r] = valid ? sc[r] : -1e30f;
      mloc = fmaxf(mloc, sc[r]);
      if (n16 == 0 && m < 8 && sg < 224) sm.scores[sg] = sc[r];
    }
    mloc = fmaxf(mloc, __shfl_xor(mloc, 16));
    mloc = fmaxf(mloc, __shfl_xor(mloc, 32));
    float m_new = fmaxf(m_run, mloc);
    float fac = __expf(m_run - m_new);
    float psum = 0.f;
    #pragma unroll
    for (int r = 0; r < 4; ++r) {
      p[r] = (sc[r] > -1e29f) ? __expf(sc[r] - m_new) : 0.f;
      psum += p[r];
    }
    psum += __shfl_xor(psum, 16);
    psum += __shfl_xor(psum, 32);
    l_run = l_run * fac + psum;
    m_run = m_new;

    float pv[8];
    #pragma unroll
    for (int s2 = 0; s2 < 8; ++s2)
      pv[s2] = __shfl(p[s2 & 3], (s2 >> 2) * 16);
    o[0] *= fac; o[1] *= fac; o[2] *= fac; o[3] *= fac;
    if (lane < 48) {
      #pragma unroll
      for (int s2 = 0; s2 < 8; ++s2) {
        bf16x4 kv = *(const bf16x4*)&cur[(wave*8 + s2)*400 + lane*8];
        o[0] += pv[s2] * (float)kv[0];
        o[1] += pv[s2] * (float)kv[1];
        o[2] += pv[s2] * (float)kv[2];
        o[3] += pv[s2] * (float)kv[3];
      }
    }
    __syncthreads();   // cur free for restage; h1buf free
  }

  // ---- combine 4 per-wave states, finalize ----
  if (lane == 0) { sm.fin.wm[wave] = m_run; sm.fin.wl[wave] = l_run; }
  if (lane < 48) *(f32x4*)&sm.fin.opart[wave][lane*4] = o;
  __syncthreads();
  float mg = fmaxf(fmaxf(sm.fin.wm[0], sm.fin.wm[1]), fmaxf(sm.fin.wm[2], sm.fin.wm[3]));
  float e0 = __expf(sm.fin.wm[0] - mg), e1 = __expf(sm.fin.wm[1] - mg);
  float e2 = __expf(sm.fin.wm[2] - mg), e3 = __expf(sm.fin.wm[3] - mg);
  float lg = sm.fin.wl[0]*e0 + sm.fin.wl[1]*e1 + sm.fin.wl[2]*e2 + sm.fin.wl[3]*e3;
  float invl = (lg > 0.f) ? 1.f / lg : 0.f;
  if (tid < 192) {
    float os = sm.fin.opart[0][tid]*e0 + sm.fin.opart[1][tid]*e1
             + sm.fin.opart[2][tid]*e2 + sm.fin.opart[3][tid]*e3;
    out[(size_t)b * D_N + tid] = os * invl;
  }
  if (tid < 200) {
    float wv = (lg > 0.f) ? __expf(sm.scores[tid] - mg) * invl : 0.f;
    out[(size_t)B_N * D_N + (size_t)b * S_N + tid] = wv;
  }
}

extern "C" void kernel_launch(void* const* d_in, const int* in_sizes, int n_in,
                              void* d_out, int out_size, void* d_ws, size_t ws_size,
                              hipStream_t stream) {
  const float* query     = (const float*)d_in[0];
  const float* keys      = (const float*)d_in[1];
  const int*   keys_mask = (const int*)  d_in[2];
  const float* W1        = (const float*)d_in[3];
  const float* b1        = (const float*)d_in[4];
  const float* a1        = (const float*)d_in[5];
  const float* W2        = (const float*)d_in[6];
  const float* b2        = (const float*)d_in[7];
  const float* a2        = (const float*)d_in[8];
  const float* W3        = (const float*)d_in[9];
  const float* b3        = (const float*)d_in[10];
  float* out = (float*)d_out;
  rich_attn_kernel<<<dim3(B_N), dim3(256), 0, stream>>>(
      query, keys, keys_mask, W1, b1, a1, W2, b2, a2, W3, b3, out);
}